// Round 4
// baseline (1312.089 us; speedup 1.0000x reference)
//
#include <hip/hip_runtime.h>
#include <cstdint>
#include <cfloat>
#include <cstddef>

#define MAXK 128

typedef __attribute__((ext_vector_type(8))) short bf16x8;
typedef __attribute__((ext_vector_type(4))) float f32x4;

// ---------------------------------------------------------------------------
// split 8 fp32 -> hi-bf16 x8 (uint4) + lo-bf16 x8 (uint4)
// ---------------------------------------------------------------------------
__device__ __forceinline__ void split8(const float4& v0, const float4& v1,
                                       uint4& hp, uint4& lp)
{
    float vv[8] = {v0.x, v0.y, v0.z, v0.w, v1.x, v1.y, v1.z, v1.w};
    unsigned h[8], l[8];
    #pragma unroll
    for (int i = 0; i < 8; ++i) {
        unsigned u  = __float_as_uint(vv[i]);
        unsigned hb = u & 0xFFFF0000u;
        float lf    = vv[i] - __uint_as_float(hb);
        h[i] = u;
        l[i] = __float_as_uint(lf);
    }
    hp.x = (h[0] >> 16) | (h[1] & 0xFFFF0000u);
    hp.y = (h[2] >> 16) | (h[3] & 0xFFFF0000u);
    hp.z = (h[4] >> 16) | (h[5] & 0xFFFF0000u);
    hp.w = (h[6] >> 16) | (h[7] & 0xFFFF0000u);
    lp.x = (l[0] >> 16) | (l[1] & 0xFFFF0000u);
    lp.y = (l[2] >> 16) | (l[3] & 0xFFFF0000u);
    lp.z = (l[4] >> 16) | (l[5] & 0xFFFF0000u);
    lp.w = (l[6] >> 16) | (l[7] & 0xFFFF0000u);
}

// async global -> LDS, 16B per lane. LDS dest = wave-uniform base + lane*16.
__device__ __forceinline__ void gload_lds16(const void* g, void* l)
{
    __builtin_amdgcn_global_load_lds(
        (const __attribute__((address_space(1))) unsigned int*)g,
        (__attribute__((address_space(3))) unsigned int*)l,
        16, 0, 0);
}

// ---------------------------------------------------------------------------
// prep_x: (x - b_dec) -> split bf16 hi/lo, tile-packed + pre-swizzled.
// ---------------------------------------------------------------------------
__global__ __launch_bounds__(256)
void prep_x_kernel(const float* __restrict__ x, const float* __restrict__ b_dec,
                   ushort* __restrict__ AhiP, ushort* __restrict__ AloP, int D)
{
    const int c   = blockIdx.x * 256 + threadIdx.x;
    const int t   = c >> 9;
    const int wc  = c & 511;
    const int rl  = wc >> 2;
    const int pkc = wc & 3;
    const int kc  = (pkc - (rl >> 1)) & 3;
    const int nkb = D >> 5;
    const int band = t / nkb, kblk = t - band * nkb;
    const int row = band * 128 + rl;
    const int k0  = kblk * 32 + kc * 8;

    const float* src = x + (size_t)row * D + k0;
    float4 v0 = *(const float4*)(src);
    float4 v1 = *(const float4*)(src + 4);
    const float* bd = b_dec + k0;
    float4 d0 = *(const float4*)(bd);
    float4 d1 = *(const float4*)(bd + 4);
    v0.x -= d0.x; v0.y -= d0.y; v0.z -= d0.z; v0.w -= d0.w;
    v1.x -= d1.x; v1.y -= d1.y; v1.z -= d1.z; v1.w -= d1.w;
    uint4 hp, lp;
    split8(v0, v1, hp, lp);
    const size_t off = (size_t)t * 4096 + (size_t)wc * 8;
    *(uint4*)&AhiP[off] = hp;
    *(uint4*)&AloP[off] = lp;
}

// ---------------------------------------------------------------------------
// prep_w: W_enc -> split bf16 hi/lo, tile-packed + pre-swizzled.
// ---------------------------------------------------------------------------
__global__ __launch_bounds__(256)
void prep_w_kernel(const float* __restrict__ Wenc,
                   ushort* __restrict__ WhiP, ushort* __restrict__ WloP, int D)
{
    const int c   = blockIdx.x * 256 + threadIdx.x;
    const int t   = c >> 10;
    const int wc  = c & 1023;
    const int rl  = wc >> 2;
    const int pkc = wc & 3;
    const int kc  = (pkc - (rl >> 1)) & 3;
    const int nkb = D >> 5;
    const int fband = t / nkb, kblk = t - fband * nkb;
    const int f   = fband * 256 + rl;
    const int k0  = kblk * 32 + kc * 8;

    const float* src = Wenc + (size_t)f * D + k0;
    float4 v0 = *(const float4*)(src);
    float4 v1 = *(const float4*)(src + 4);
    uint4 hp, lp;
    split8(v0, v1, hp, lp);
    const size_t off = (size_t)t * 8192 + (size_t)wc * 8;
    *(uint4*)&WhiP[off] = hp;
    *(uint4*)&WloP[off] = lp;
}

// ---------------------------------------------------------------------------
// Encode GEMM, pre-split operands, 2-phase double-buffered staging:
// stage(kb+1) issued BEFORE compute(kb) so global_load_lds latency hides
// under the 96-MFMA phase; one vmcnt(0)+barrier per K-step.
// XCD-chunked swizzle: each XCD owns a contiguous bn range (bm fastest) so
// the resident blocks of an XCD share one 2MB B-panel in its private L2.
// LDS 96 KB -> 1 block/CU.
// ---------------------------------------------------------------------------
__global__ __launch_bounds__(256, 1)
void encode_gemm_db(const ushort* __restrict__ AhiP, const ushort* __restrict__ AloP,
                    const ushort* __restrict__ WhiP, const ushort* __restrict__ WloP,
                    const float* __restrict__ b_enc, float* __restrict__ z_pre,
                    int D, int F, int nbm)
{
    __shared__ ushort AsHi0[4096], AsLo0[4096];
    __shared__ ushort BsHi0[8192], BsLo0[8192];
    __shared__ ushort AsHi1[4096], AsLo1[4096];
    __shared__ ushort BsHi1[8192], BsLo1[8192];   // total 96 KB

    const int tid = threadIdx.x;
    const int nwg = gridDim.x;
    int lb = blockIdx.x;
    if ((nwg & 7) == 0) {
        const int per = nwg >> 3;
        lb = (blockIdx.x & 7) * per + (blockIdx.x >> 3);
    }
    const int bm = (lb % nbm) * 128;      // bm fastest within an XCD chunk
    const int bn = (lb / nbm) * 256;

    const int lane = tid & 63;
    const int w    = tid >> 6;
    const int wm   = (w >> 1) * 64;
    const int wn   = (w & 1) * 128;
    const int fr   = lane & 15;
    const int q    = lane >> 4;
    const int nkb  = D >> 5;

    int aoff[4], boff[8];
    #pragma unroll
    for (int mi = 0; mi < 4; ++mi) {
        const int r = wm + mi * 16 + fr;
        aoff[mi] = r * 32 + (((q + (r >> 1)) & 3) * 8);
    }
    #pragma unroll
    for (int ni = 0; ni < 8; ++ni) {
        const int r = wn + ni * 16 + fr;
        boff[ni] = r * 32 + (((q + (r >> 1)) & 3) * 8);
    }

    f32x4 acc[4][8];
    #pragma unroll
    for (int mi = 0; mi < 4; ++mi)
        #pragma unroll
        for (int ni = 0; ni < 8; ++ni)
            acc[mi][ni] = (f32x4){0.f, 0.f, 0.f, 0.f};

    const char* aHi = (const char*)AhiP + (size_t)(bm >> 7) * nkb * 8192;
    const char* aLo = (const char*)AloP + (size_t)(bm >> 7) * nkb * 8192;
    const char* bHi = (const char*)WhiP + (size_t)(bn >> 8) * nkb * 16384;
    const char* bLo = (const char*)WloP + (size_t)(bn >> 8) * nkb * 16384;
    const int la16 = lane * 16;

    auto stage = [&](int kb, ushort* dAH, ushort* dAL, ushort* dBH, ushort* dBL) {
        const char* pa = aHi + (size_t)kb * 8192;
        const char* pl = aLo + (size_t)kb * 8192;
        const char* pb = bHi + (size_t)kb * 16384;
        const char* pm = bLo + (size_t)kb * 16384;
        #pragma unroll
        for (int c = 0; c < 2; ++c) {
            const int off = (w * 2 + c) * 1024;
            gload_lds16(pa + off + la16, (char*)dAH + off);
            gload_lds16(pl + off + la16, (char*)dAL + off);
        }
        #pragma unroll
        for (int c = 0; c < 4; ++c) {
            const int off = (w * 4 + c) * 1024;
            gload_lds16(pb + off + la16, (char*)dBH + off);
            gload_lds16(pm + off + la16, (char*)dBL + off);
        }
    };

    auto compute = [&](const ushort* sAH, const ushort* sAL,
                       const ushort* sBH, const ushort* sBL) {
        bf16x8 ahi[4], alo[4];
        #pragma unroll
        for (int mi = 0; mi < 4; ++mi) {
            ahi[mi] = *(const bf16x8*)&sAH[aoff[mi]];
            alo[mi] = *(const bf16x8*)&sAL[aoff[mi]];
        }
        #pragma unroll
        for (int ni = 0; ni < 8; ++ni) {
            bf16x8 bhi = *(const bf16x8*)&sBH[boff[ni]];
            bf16x8 blo = *(const bf16x8*)&sBL[boff[ni]];
            #pragma unroll
            for (int mi = 0; mi < 4; ++mi) {
                acc[mi][ni] = __builtin_amdgcn_mfma_f32_16x16x32_bf16(alo[mi], bhi, acc[mi][ni], 0, 0, 0);
                acc[mi][ni] = __builtin_amdgcn_mfma_f32_16x16x32_bf16(ahi[mi], blo, acc[mi][ni], 0, 0, 0);
                acc[mi][ni] = __builtin_amdgcn_mfma_f32_16x16x32_bf16(ahi[mi], bhi, acc[mi][ni], 0, 0, 0);
            }
        }
    };

    stage(0, AsHi0, AsLo0, BsHi0, BsLo0);
    asm volatile("s_waitcnt vmcnt(0)" ::: "memory");
    __syncthreads();

    for (int kb = 0; kb < nkb; kb += 2) {   // nkb even (D % 64 == 0)
        if (kb + 1 < nkb) stage(kb + 1, AsHi1, AsLo1, BsHi1, BsLo1);
        compute(AsHi0, AsLo0, BsHi0, BsLo0);
        asm volatile("s_waitcnt vmcnt(0)" ::: "memory");
        __syncthreads();
        if (kb + 2 < nkb) stage(kb + 2, AsHi0, AsLo0, BsHi0, BsLo0);
        compute(AsHi1, AsLo1, BsHi1, BsLo1);
        asm volatile("s_waitcnt vmcnt(0)" ::: "memory");
        __syncthreads();
    }

    // ---- epilogue: +b_enc, store (C/D map: row = q*4+r, col = fr) ----
    #pragma unroll
    for (int ni = 0; ni < 8; ++ni) {
        const int col = bn + wn + ni * 16 + fr;
        const float be = b_enc[col];
        #pragma unroll
        for (int mi = 0; mi < 4; ++mi) {
            const int rbase = bm + wm + mi * 16 + q * 4;
            float* dst = z_pre + (size_t)rbase * F + col;
            #pragma unroll
            for (int r = 0; r < 4; ++r)
                dst[(size_t)r * F] = acc[mi][ni][r] + be;
        }
    }
}

// ---------------------------------------------------------------------------
// Single-buffered pre-split GEMM (used when D%64 != 0 but D%32 == 0).
// ---------------------------------------------------------------------------
__global__ __launch_bounds__(256, 2)
void encode_gemm_pre(const ushort* __restrict__ AhiP, const ushort* __restrict__ AloP,
                     const ushort* __restrict__ WhiP, const ushort* __restrict__ WloP,
                     const float* __restrict__ b_enc, float* __restrict__ z_pre,
                     int D, int F)
{
    __shared__ ushort AsHi[4096];
    __shared__ ushort AsLo[4096];
    __shared__ ushort BsHi[8192];
    __shared__ ushort BsLo[8192];

    const int tid = threadIdx.x;
    const int bm  = blockIdx.y * 128;
    const int bn  = blockIdx.x * 256;

    const int lane = tid & 63;
    const int w    = tid >> 6;
    const int wm   = (w >> 1) * 64;
    const int wn   = (w & 1) * 128;
    const int fr   = lane & 15;
    const int q    = lane >> 4;
    const int nkb  = D >> 5;

    int aoff[4], boff[8];
    #pragma unroll
    for (int mi = 0; mi < 4; ++mi) {
        const int r = wm + mi * 16 + fr;
        aoff[mi] = r * 32 + (((q + (r >> 1)) & 3) * 8);
    }
    #pragma unroll
    for (int ni = 0; ni < 8; ++ni) {
        const int r = wn + ni * 16 + fr;
        boff[ni] = r * 32 + (((q + (r >> 1)) & 3) * 8);
    }

    f32x4 acc[4][8];
    #pragma unroll
    for (int mi = 0; mi < 4; ++mi)
        #pragma unroll
        for (int ni = 0; ni < 8; ++ni)
            acc[mi][ni] = (f32x4){0.f, 0.f, 0.f, 0.f};

    const char* aHi = (const char*)AhiP + (size_t)blockIdx.y * nkb * 8192;
    const char* aLo = (const char*)AloP + (size_t)blockIdx.y * nkb * 8192;
    const char* bHi = (const char*)WhiP + (size_t)blockIdx.x * nkb * 16384;
    const char* bLo = (const char*)WloP + (size_t)blockIdx.x * nkb * 16384;
    const int la16 = lane * 16;

    for (int kb = 0; kb < nkb; ++kb) {
        const char* pa = aHi + (size_t)kb * 8192;
        const char* pl = aLo + (size_t)kb * 8192;
        const char* pb = bHi + (size_t)kb * 16384;
        const char* pm = bLo + (size_t)kb * 16384;

        #pragma unroll
        for (int c = 0; c < 2; ++c) {
            const int off = (w * 2 + c) * 1024;
            gload_lds16(pa + off + la16, (char*)AsHi + off);
            gload_lds16(pl + off + la16, (char*)AsLo + off);
        }
        #pragma unroll
        for (int c = 0; c < 4; ++c) {
            const int off = (w * 4 + c) * 1024;
            gload_lds16(pb + off + la16, (char*)BsHi + off);
            gload_lds16(pm + off + la16, (char*)BsLo + off);
        }
        asm volatile("s_waitcnt vmcnt(0)" ::: "memory");
        __syncthreads();

        bf16x8 ahi[4], alo[4];
        #pragma unroll
        for (int mi = 0; mi < 4; ++mi) {
            ahi[mi] = *(const bf16x8*)&AsHi[aoff[mi]];
            alo[mi] = *(const bf16x8*)&AsLo[aoff[mi]];
        }
        #pragma unroll
        for (int ni = 0; ni < 8; ++ni) {
            bf16x8 bhi = *(const bf16x8*)&BsHi[boff[ni]];
            bf16x8 blo = *(const bf16x8*)&BsLo[boff[ni]];
            #pragma unroll
            for (int mi = 0; mi < 4; ++mi) {
                acc[mi][ni] = __builtin_amdgcn_mfma_f32_16x16x32_bf16(alo[mi], bhi, acc[mi][ni], 0, 0, 0);
                acc[mi][ni] = __builtin_amdgcn_mfma_f32_16x16x32_bf16(ahi[mi], blo, acc[mi][ni], 0, 0, 0);
                acc[mi][ni] = __builtin_amdgcn_mfma_f32_16x16x32_bf16(ahi[mi], bhi, acc[mi][ni], 0, 0, 0);
            }
        }
        __syncthreads();
    }

    #pragma unroll
    for (int ni = 0; ni < 8; ++ni) {
        const int col = bn + wn + ni * 16 + fr;
        const float be = b_enc[col];
        #pragma unroll
        for (int mi = 0; mi < 4; ++mi) {
            const int rbase = bm + wm + mi * 16 + q * 4;
            float* dst = z_pre + (size_t)rbase * F + col;
            #pragma unroll
            for (int r = 0; r < 4; ++r)
                dst[(size_t)r * F] = acc[mi][ni][r] + be;
        }
    }
}

// ---------------------------------------------------------------------------
// Fallback encode GEMM (reg-staged split) — used only if workspace too small.
// ---------------------------------------------------------------------------
__global__ __launch_bounds__(256, 2)
void encode_gemm_bf16x3(const float* __restrict__ x, const float* __restrict__ Wenc,
                        const float* __restrict__ b_enc, const float* __restrict__ b_dec,
                        float* __restrict__ z_pre, int D, int F)
{
    constexpr int BM = 128, BN = 256, BK = 32;
    __shared__ ushort AsHi[BM * BK];
    __shared__ ushort AsLo[BM * BK];
    __shared__ ushort BsHi[BN * BK];
    __shared__ ushort BsLo[BN * BK];

    const int tid = threadIdx.x;
    const int bm  = blockIdx.y * BM;
    const int bn  = blockIdx.x * BN;

    const int lane = tid & 63;
    const int w    = tid >> 6;
    const int wm   = (w >> 1) * 64;
    const int wn   = (w & 1) * 128;
    const int fr   = lane & 15;
    const int q    = lane >> 4;

    int aoff[4], boff[8];
    #pragma unroll
    for (int mi = 0; mi < 4; ++mi) {
        const int r = wm + mi * 16 + fr;
        aoff[mi] = r * 32 + (((q + (r >> 1)) & 3) * 8);
    }
    #pragma unroll
    for (int ni = 0; ni < 8; ++ni) {
        const int r = wn + ni * 16 + fr;
        boff[ni] = r * 32 + (((q + (r >> 1)) & 3) * 8);
    }

    f32x4 acc[4][8];
    #pragma unroll
    for (int mi = 0; mi < 4; ++mi)
        #pragma unroll
        for (int ni = 0; ni < 8; ++ni)
            acc[mi][ni] = (f32x4){0.f, 0.f, 0.f, 0.f};

    for (int k0 = 0; k0 < D; k0 += BK) {
        #pragma unroll
        for (int j = 0; j < 2; ++j) {
            const int task = tid + 256 * j;
            const int row = task >> 2, kc = task & 3;
            const float* src = x + (size_t)(bm + row) * D + k0 + kc * 8;
            float4 v0 = *(const float4*)(src);
            float4 v1 = *(const float4*)(src + 4);
            const float* bd = b_dec + k0 + kc * 8;
            float4 d0 = *(const float4*)(bd);
            float4 d1 = *(const float4*)(bd + 4);
            v0.x -= d0.x; v0.y -= d0.y; v0.z -= d0.z; v0.w -= d0.w;
            v1.x -= d1.x; v1.y -= d1.y; v1.z -= d1.z; v1.w -= d1.w;
            uint4 hp, lp;
            split8(v0, v1, hp, lp);
            const int off = row * 32 + (((kc + (row >> 1)) & 3) * 8);
            *(uint4*)&AsHi[off] = hp;
            *(uint4*)&AsLo[off] = lp;
        }
        #pragma unroll
        for (int j = 0; j < 4; ++j) {
            const int task = tid + 256 * j;
            const int row = task >> 2, kc = task & 3;
            const float* src = Wenc + (size_t)(bn + row) * D + k0 + kc * 8;
            float4 v0 = *(const float4*)(src);
            float4 v1 = *(const float4*)(src + 4);
            uint4 hp, lp;
            split8(v0, v1, hp, lp);
            const int off = row * 32 + (((kc + (row >> 1)) & 3) * 8);
            *(uint4*)&BsHi[off] = hp;
            *(uint4*)&BsLo[off] = lp;
        }
        __syncthreads();

        bf16x8 ahi[4], alo[4];
        #pragma unroll
        for (int mi = 0; mi < 4; ++mi) {
            ahi[mi] = *(const bf16x8*)&AsHi[aoff[mi]];
            alo[mi] = *(const bf16x8*)&AsLo[aoff[mi]];
        }
        #pragma unroll
        for (int ni = 0; ni < 8; ++ni) {
            bf16x8 bhi = *(const bf16x8*)&BsHi[boff[ni]];
            bf16x8 blo = *(const bf16x8*)&BsLo[boff[ni]];
            #pragma unroll
            for (int mi = 0; mi < 4; ++mi) {
                acc[mi][ni] = __builtin_amdgcn_mfma_f32_16x16x32_bf16(alo[mi], bhi, acc[mi][ni], 0, 0, 0);
                acc[mi][ni] = __builtin_amdgcn_mfma_f32_16x16x32_bf16(ahi[mi], blo, acc[mi][ni], 0, 0, 0);
                acc[mi][ni] = __builtin_amdgcn_mfma_f32_16x16x32_bf16(ahi[mi], bhi, acc[mi][ni], 0, 0, 0);
            }
        }
        __syncthreads();
    }

    #pragma unroll
    for (int ni = 0; ni < 8; ++ni) {
        const int col = bn + wn + ni * 16 + fr;
        const float be = b_enc[col];
        #pragma unroll
        for (int mi = 0; mi < 4; ++mi) {
            const int rbase = bm + wm + mi * 16 + q * 4;
            float* dst = z_pre + (size_t)rbase * F + col;
            #pragma unroll
            for (int r = 0; r < 4; ++r)
                dst[(size_t)r * F] = acc[mi][ni][r] + be;
        }
    }
}

// ---------------------------------------------------------------------------
// Monotonic uint key for float ordering
// ---------------------------------------------------------------------------
__device__ __forceinline__ unsigned fkey(float f)
{
    unsigned u = __float_as_uint(f);
    return u ^ ((unsigned)((int)u >> 31) | 0x80000000u);
}
__device__ __forceinline__ float finv(unsigned k)
{
    unsigned u = (k & 0x80000000u) ? (k ^ 0x80000000u) : ~k;
    return __uint_as_float(u);
}

// exact fp32 dot for feature f over one wave; valid result on ln==0 only
__device__ __forceinline__ float exact_zpre(const float* __restrict__ xr,
                                            const float* __restrict__ Wenc,
                                            const float* __restrict__ b_enc,
                                            const float* __restrict__ b_dec,
                                            int f, int D, int ln)
{
    const float* wr = Wenc + (size_t)f * D;
    float s = 0.f;
    for (int d = ln * 4; d < D; d += 256) {
        float4 xv = *(const float4*)(xr + d);
        float4 bd = *(const float4*)(b_dec + d);
        float4 wv4 = *(const float4*)(wr + d);
        s = fmaf(xv.x - bd.x, wv4.x, s);
        s = fmaf(xv.y - bd.y, wv4.y, s);
        s = fmaf(xv.z - bd.z, wv4.z, s);
        s = fmaf(xv.w - bd.w, wv4.w, s);
    }
    #pragma unroll
    for (int o = 32; o > 0; o >>= 1) s += __shfl_down(s, o, 64);
    return s + b_enc[f];
}

// ---------------------------------------------------------------------------
// topk_fast: single-stream top-k (zero-fill of z fused into pass 1).
// ---------------------------------------------------------------------------
#define DLT 4e-3f

template <int NVEC>
__global__ __launch_bounds__(256)
void topk_fast(const float* __restrict__ z_pre, float* __restrict__ z,
               float* __restrict__ ws_vals, int* __restrict__ ws_idx,
               const int* __restrict__ k_ptr,
               const float* __restrict__ x, const float* __restrict__ Wenc,
               const float* __restrict__ b_enc, const float* __restrict__ b_dec,
               int F, int D)
{
    const int row = blockIdx.x;
    const int t   = threadIdx.x;
    const int k   = *k_ptr;
    const int nv4 = F >> 2;
    const int wv_id = t >> 6, ln = t & 63;

    __shared__ ushort keys[16384];          // 32 KB
    __shared__ float  cand_v[256];
    __shared__ int    cand_i[256];
    __shared__ unsigned char cand_sel[256];
    __shared__ int    bnd[128];
    __shared__ float  s2w[4];
    __shared__ int    hist4[4][256];        // fallback only
    __shared__ int    waveTot[4];
    __shared__ int    s_bin, s_above;
    __shared__ int    n_c_s, n_b_s, c_hi_s, out_cnt, cnt_tau_s, bad_s;
    __shared__ unsigned vk_key;

    if (t == 0) {
        n_c_s = 0; n_b_s = 0; c_hi_s = 0; out_cnt = 0; cnt_tau_s = 0; bad_s = 0;
        vk_key = 0xFFFFFFFFu;
    }

    const float*  zrow = z_pre + (size_t)row * F;
    const float4* src  = (const float4*)zrow;
    float4* dstz = (float4*)(z + (size_t)row * F);
    const float4 zz = make_float4(0.f, 0.f, 0.f, 0.f);

    // ---- pass 1: stream z_pre once: sum v^2 + bf16 keys to LDS + z zero-fill
    float s2 = 0.f;
    #pragma unroll
    for (int i = 0; i < NVEC; ++i) {
        const int p = t + 256 * i;
        if (p < nv4) {
            const float4 v = src[p];
            dstz[p] = zz;                   // overlapped with read stream
            const unsigned k0 = fkey(v.x) >> 16;
            const unsigned k1 = fkey(v.y) >> 16;
            const unsigned k2 = fkey(v.z) >> 16;
            const unsigned k3 = fkey(v.w) >> 16;
            uint2 pk;
            pk.x = k0 | (k1 << 16);
            pk.y = k2 | (k3 << 16);
            *(uint2*)&keys[p * 4] = pk;
            s2 = fmaf(v.x, v.x, s2);
            s2 = fmaf(v.y, v.y, s2);
            s2 = fmaf(v.z, v.z, s2);
            s2 = fmaf(v.w, v.w, s2);
        }
    }
    #pragma unroll
    for (int o = 32; o > 0; o >>= 1) s2 += __shfl_down(s2, o, 64);
    if (ln == 0) s2w[wv_id] = s2;
    __syncthreads();

    const float sigma = sqrtf((s2w[0] + s2w[1] + s2w[2] + s2w[3]) / (float)F);
    int c0 = 4 * k; if (c0 < 64) c0 = 64; if (c0 > 192) c0 = 192;
    const float qq  = (float)c0 / (float)F;
    const float tt  = sqrtf(-2.f * logf(qq));
    const float phi = tt - (2.30753f + 0.27061f * tt) /
                           (1.f + 0.99229f * tt + 0.04481f * tt * tt);
    const float tau = sigma * phi;
    const unsigned tk = fkey(tau) >> 16;
    const unsigned tkey16 = (tk >= 2) ? (tk - 2) : 0;

    // ---- pass 2: scan LDS keys, collect candidate indices ----
    const int nU = nv4 * 2;
    const unsigned* keysU = (const unsigned*)keys;
    for (int j = t; j < nU; j += 256) {
        const unsigned pr = keysU[j];
        const unsigned ka = pr & 0xFFFFu, kb = pr >> 16;
        if (ka > tkey16) { const int s = atomicAdd(&n_c_s, 1); if (s < 256) cand_i[s] = 2 * j; }
        if (kb > tkey16) { const int s = atomicAdd(&n_c_s, 1); if (s < 256) cand_i[s] = 2 * j + 1; }
    }
    __syncthreads();

    if (t == 0 && (n_c_s > 256 || !(tau > 0.1f))) bad_s = 1;
    const int n_c = min(n_c_s, 256);

    float myv = 0.f;
    if (t < n_c) {
        myv = zrow[cand_i[t]];
        cand_v[t] = myv;
        if (myv > tau) atomicAdd(&cnt_tau_s, 1);
    }
    __syncthreads();
    if (t == 0 && cnt_tau_s < k) bad_s = 1;

    cand_sel[t] = 0;
    if (t < n_c) {
        int gt = 0;
        for (int j = 0; j < n_c; ++j) gt += (cand_v[j] > myv);
        if (gt <= k - 1) atomicMin(&vk_key, fkey(myv));
    }
    __syncthreads();

    const float vkv = finv(vk_key);
    if (t < n_c) {
        if (myv > vkv + DLT) {
            cand_sel[t] = 2;
            atomicAdd(&c_hi_s, 1);
        } else if (myv > vkv - DLT) {
            const int sb = atomicAdd(&n_b_s, 1);
            if (sb < 128) bnd[sb] = t;
        }
    }
    __syncthreads();
    if (t == 0 && n_b_s > 128) bad_s = 1;
    __syncthreads();

    if (!bad_s) {
        const int n_b = n_b_s;
        const float* xr = x + (size_t)row * D;
        for (int b2 = wv_id; b2 < n_b; b2 += 4) {
            const int c = bnd[b2];
            const float ex = exact_zpre(xr, Wenc, b_enc, b_dec, cand_i[c], D, ln);
            if (ln == 0) cand_v[c] = ex;
        }
        __syncthreads();

        if (t == 0) {
            int need = k - c_hi_s;
            if (need > n_b) need = n_b;
            for (int it = 0; it < need; ++it) {
                int bi = -1; float bv = 0.f;
                for (int b2 = 0; b2 < n_b; ++b2) {
                    const int c = bnd[b2];
                    if (cand_sel[c]) continue;
                    const float v = cand_v[c];
                    if (bi < 0 || v > bv || (v == bv && cand_i[c] < cand_i[bi])) {
                        bi = c; bv = v;
                    }
                }
                if (bi < 0) break;
                cand_sel[bi] = 1;
            }
        }
        __syncthreads();

        float* wvp = ws_vals + (size_t)row * MAXK;
        int*   wip = ws_idx  + (size_t)row * MAXK;
        if (t < n_c && cand_sel[t]) {
            const float zv = fmaxf(cand_v[t], 0.f);
            z[(size_t)row * F + cand_i[t]] = zv;
            const int s = atomicAdd(&out_cnt, 1);
            if (s < MAXK) { wvp[s] = zv; wip[s] = cand_i[t]; }
        }
        return;
    }

    // ================= fallback: 2-pass radix on global fp32 =================
    if (t == 0) { n_c_s = 0; c_hi_s = 0; out_cnt = 0; }
    __syncthreads();

    unsigned prefix = 0;
    int rem = k;
    for (int pass = 0; pass < 2; ++pass) {
        const int shift = 24 - 8 * pass;
        hist4[0][t] = 0; hist4[1][t] = 0; hist4[2][t] = 0; hist4[3][t] = 0;
        __syncthreads();
        for (int j = t; j < F; j += 256) {
            const unsigned key = fkey(zrow[j]);
            const bool inb = (pass == 0) || ((key >> (shift + 8)) == prefix);
            if (inb) atomicAdd(&hist4[wv_id][(key >> shift) & 255], 1);
        }
        __syncthreads();
        const int cnt = hist4[0][t] + hist4[1][t] + hist4[2][t] + hist4[3][t];
        int s = cnt;
        #pragma unroll
        for (int off = 1; off < 64; off <<= 1) {
            const int tmp = __shfl_down(s, off, 64);
            if (ln + off < 64) s += tmp;
        }
        if (ln == 0) waveTot[wv_id] = s;
        __syncthreads();
        int add = 0;
        #pragma unroll
        for (int w2 = 0; w2 < 4; ++w2)
            if (w2 > wv_id) add += waveTot[w2];
        const int sfx = s + add;
        const int nxt = sfx - cnt;
        if (sfx >= rem && nxt < rem) { s_bin = t; s_above = nxt; }
        __syncthreads();
        rem -= s_above;
        prefix = (prefix << 8) | (unsigned)s_bin;
        __syncthreads();
    }

    const float hiT = finv((prefix << 16) | 0xFFFFu) + DLT;
    const float loT = finv(prefix << 16) - DLT;

    for (int j = t; j < F; j += 256) {
        const float v = zrow[j];
        if (v > hiT) atomicAdd(&c_hi_s, 1);
        else if (v > loT) {
            const int s = atomicAdd(&n_c_s, 1);
            if (s < 256) { cand_i[s] = j; cand_sel[s] = 0; }
        }
    }
    __syncthreads();
    const int n_c2 = min(n_c_s, 256);

    {
        const float* xr = x + (size_t)row * D;
        for (int c = wv_id; c < n_c2; c += 4) {
            const float ex = exact_zpre(xr, Wenc, b_enc, b_dec, cand_i[c], D, ln);
            if (ln == 0) cand_v[c] = ex;
        }
    }
    __syncthreads();

    if (t == 0) {
        int need = k - c_hi_s;
        if (need > n_c2) need = n_c2;
        for (int it = 0; it < need; ++it) {
            int bi = -1; float bv = 0.f;
            for (int c = 0; c < n_c2; ++c) {
                if (cand_sel[c]) continue;
                const float v = cand_v[c];
                if (bi < 0 || v > bv || (v == bv && cand_i[c] < cand_i[bi])) {
                    bi = c; bv = v;
                }
            }
            if (bi < 0) break;
            cand_sel[bi] = 1;
        }
    }
    __syncthreads();

    {
        const float4 z4 = make_float4(0.f, 0.f, 0.f, 0.f);
        #pragma unroll
        for (int i = 0; i < NVEC; ++i) {
            const int p = t + 256 * i;
            if (p < nv4) dstz[p] = z4;
        }
    }
    __syncthreads();

    float* wvp = ws_vals + (size_t)row * MAXK;
    int*   wip = ws_idx  + (size_t)row * MAXK;
    for (int j = t; j < F; j += 256) {
        const float v = zrow[j];
        if (v > hiT) {
            const float zv = fmaxf(v, 0.f);
            z[(size_t)row * F + j] = zv;
            const int s = atomicAdd(&out_cnt, 1);
            if (s < MAXK) { wvp[s] = zv; wip[s] = j; }
        }
    }
    if (t < n_c2 && cand_sel[t]) {
        const float zv = fmaxf(cand_v[t], 0.f);
        z[(size_t)row * F + cand_i[t]] = zv;
        const int s = atomicAdd(&out_cnt, 1);
        if (s < MAXK) { wvp[s] = zv; wip[s] = cand_i[t]; }
    }
}

// ---------------------------------------------------------------------------
// Generic per-row top-k (register/reload variant) — only for F > 16384.
// ---------------------------------------------------------------------------
template <int NVEC>
__global__ __launch_bounds__(256)
void topk_kernel(const float* __restrict__ z_pre, float* __restrict__ z,
                 float* __restrict__ ws_vals, int* __restrict__ ws_idx,
                 const int* __restrict__ k_ptr,
                 const float* __restrict__ x, const float* __restrict__ Wenc,
                 const float* __restrict__ b_enc, const float* __restrict__ b_dec,
                 int F, int D)
{
    const int row = blockIdx.x;
    const int t   = threadIdx.x;
    const int k   = *k_ptr;
    const int nv4 = F >> 2;
    const int wv_id = t >> 6;
    const int ln    = t & 63;

    const float4* src = (const float4*)(z_pre + (size_t)row * F);
    float4 vals[NVEC];
    #pragma unroll
    for (int i = 0; i < NVEC; ++i) {
        const int p = t + 256 * i;
        if (p < nv4) vals[i] = src[p];
        else         vals[i] = make_float4(-FLT_MAX, -FLT_MAX, -FLT_MAX, -FLT_MAX);
    }

    __shared__ int hist[4][256];
    __shared__ int waveTot[4];
    __shared__ int s_bin, s_above;
    __shared__ int c_hi_s, n_c_s, out_cnt;
    __shared__ int cand_idx[128];
    __shared__ float cand_val[128];
    __shared__ unsigned char cand_sel[128];

    unsigned prefix = 0;
    int rem = k;

    #pragma unroll
    for (int pass = 0; pass < 2; ++pass) {
        const int shift = 24 - 8 * pass;
        hist[0][t] = 0; hist[1][t] = 0; hist[2][t] = 0; hist[3][t] = 0;
        __syncthreads();
        #pragma unroll
        for (int i = 0; i < NVEC; ++i) {
            const float* vv = (const float*)&vals[i];
            #pragma unroll
            for (int j = 0; j < 4; ++j) {
                const unsigned key = fkey(vv[j]);
                const bool inb = (pass == 0) || ((key >> (shift + 8)) == prefix);
                if (inb) atomicAdd(&hist[wv_id][(key >> shift) & 255], 1);
            }
        }
        __syncthreads();
        const int cnt = hist[0][t] + hist[1][t] + hist[2][t] + hist[3][t];
        int s = cnt;
        #pragma unroll
        for (int off = 1; off < 64; off <<= 1) {
            const int tmp = __shfl_down(s, off, 64);
            if (ln + off < 64) s += tmp;
        }
        if (ln == 0) waveTot[wv_id] = s;
        __syncthreads();
        int add = 0;
        #pragma unroll
        for (int w2 = 0; w2 < 4; ++w2)
            if (w2 > wv_id) add += waveTot[w2];
        const int sfx = s + add;
        const int nxt = sfx - cnt;
        if (sfx >= rem && nxt < rem) { s_bin = t; s_above = nxt; }
        __syncthreads();
        rem -= s_above;
        prefix = (prefix << 8) | (unsigned)s_bin;
        __syncthreads();
    }

    const unsigned keyLo = prefix << 16;
    const unsigned keyHi = keyLo | 0xFFFFu;
    const float dlt = 1e-3f;
    const float hiThr = finv(keyHi) + dlt;
    const float loThr = finv(keyLo) - dlt;

    if (t == 0) { c_hi_s = 0; n_c_s = 0; out_cnt = 0; }
    __syncthreads();

    #pragma unroll
    for (int i = 0; i < NVEC; ++i) {
        const float* vv = (const float*)&vals[i];
        #pragma unroll
        for (int j = 0; j < 4; ++j) {
            const float v = vv[j];
            if (v > hiThr) {
                atomicAdd(&c_hi_s, 1);
            } else if (v > loThr) {
                const int s = atomicAdd(&n_c_s, 1);
                if (s < 128) { cand_idx[s] = (t + 256 * i) * 4 + j; cand_sel[s] = 0; }
            }
        }
    }
    __syncthreads();

    const int n_c = min(n_c_s, 128);

    {
        const float* xr = x + (size_t)row * D;
        for (int c = wv_id; c < n_c; c += 4) {
            const float ex = exact_zpre(xr, Wenc, b_enc, b_dec, cand_idx[c], D, ln);
            if (ln == 0) cand_val[c] = ex;
        }
    }
    __syncthreads();

    if (t == 0) {
        int need = k - c_hi_s;
        if (need > n_c) need = n_c;
        for (int it = 0; it < need; ++it) {
            int bi = -1; float bv = 0.f;
            for (int c = 0; c < n_c; ++c) {
                if (cand_sel[c]) continue;
                const float v = cand_val[c];
                if (bi < 0 || v > bv || (v == bv && cand_idx[c] < cand_idx[bi])) {
                    bi = c; bv = v;
                }
            }
            if (bi < 0) break;
            cand_sel[bi] = 1;
        }
    }
    __syncthreads();

    float4* dstz = (float4*)(z + (size_t)row * F);
    float*  wv   = ws_vals + (size_t)row * MAXK;
    int*    wi   = ws_idx  + (size_t)row * MAXK;

    #pragma unroll
    for (int i = 0; i < NVEC; ++i) {
        const int p4 = t + 256 * i;
        if (p4 < nv4) {
            const float* vv = (const float*)&vals[i];
            float4 outv;
            float* ov = (float*)&outv;
            #pragma unroll
            for (int j = 0; j < 4; ++j) {
                const int pos = p4 * 4 + j;
                const float v = vv[j];
                float zv = 0.f;
                bool sel = false;
                if (v > hiThr) {
                    zv = fmaxf(v, 0.f); sel = true;
                } else if (v > loThr) {
                    for (int c = 0; c < n_c; ++c) {
                        if (cand_idx[c] == pos) {
                            if (cand_sel[c]) { zv = fmaxf(cand_val[c], 0.f); sel = true; }
                            break;
                        }
                    }
                }
                ov[j] = zv;
                if (sel) {
                    const int s = atomicAdd(&out_cnt, 1);
                    if (s < MAXK) { wv[s] = zv; wi[s] = pos; }
                }
            }
            dstz[p4] = outv;
        }
    }
}

// ---------------------------------------------------------------------------
// Transpose W_dec [D, F] -> W_decT [F, D]
// ---------------------------------------------------------------------------
__global__ __launch_bounds__(256)
void transpose_kernel(const float* __restrict__ in, float* __restrict__ out,
                      int R, int C)
{
    __shared__ float tile[32][33];
    const int c0 = blockIdx.x * 32;
    const int r0 = blockIdx.y * 32;
    const int tx = threadIdx.x & 31;
    const int ty = threadIdx.x >> 5;

    #pragma unroll
    for (int i = ty; i < 32; i += 8) {
        const int r = r0 + i, c = c0 + tx;
        tile[i][tx] = (r < R && c < C) ? in[(size_t)r * C + c] : 0.f;
    }
    __syncthreads();
    #pragma unroll
    for (int i = ty; i < 32; i += 8) {
        const int c = c0 + i, r = r0 + tx;
        if (c < C && r < R) out[(size_t)c * R + r] = tile[tx][i];
    }
}

// ---------------------------------------------------------------------------
// Sparse decode: x_hat[b,:] = b_dec + sum_j val_j * W_decT[idx_j,:]
// ---------------------------------------------------------------------------
__global__ __launch_bounds__(256)
void decode_kernel(const float* __restrict__ WdT, const float* __restrict__ wvals,
                   const int* __restrict__ widx, const float* __restrict__ b_dec,
                   float* __restrict__ x_hat, const int* __restrict__ k_ptr, int D)
{
    __shared__ float sv[MAXK];
    __shared__ int   si[MAXK];
    const int row = blockIdx.x;
    const int t   = threadIdx.x;
    int k = *k_ptr;
    if (k > MAXK) k = MAXK;

    if (t < MAXK) {
        sv[t] = wvals[(size_t)row * MAXK + t];
        si[t] = widx [(size_t)row * MAXK + t];
    }
    __syncthreads();

    for (int d0 = t * 4; d0 < D; d0 += 1024) {
        float4 acc0 = *(const float4*)(b_dec + d0);
        float4 acc1 = make_float4(0.f, 0.f, 0.f, 0.f);
        int j = 0;
        for (; j + 2 <= k; j += 2) {
            const float v0 = sv[j],     v1 = sv[j + 1];
            const int   f0 = si[j],     f1 = si[j + 1];
            const float4 w0 = *(const float4*)(WdT + (size_t)f0 * D + d0);
            const float4 w1 = *(const float4*)(WdT + (size_t)f1 * D + d0);
            acc0.x = fmaf(v0, w0.x, acc0.x);
            acc0.y = fmaf(v0, w0.y, acc0.y);
            acc0.z = fmaf(v0, w0.z, acc0.z);
            acc0.w = fmaf(v0, w0.w, acc0.w);
            acc1.x = fmaf(v1, w1.x, acc1.x);
            acc1.y = fmaf(v1, w1.y, acc1.y);
            acc1.z = fmaf(v1, w1.z, acc1.z);
            acc1.w = fmaf(v1, w1.w, acc1.w);
        }
        if (j < k) {
            const float v0 = sv[j];
            const float4 w0 = *(const float4*)(WdT + (size_t)si[j] * D + d0);
            acc0.x = fmaf(v0, w0.x, acc0.x);
            acc0.y = fmaf(v0, w0.y, acc0.y);
            acc0.z = fmaf(v0, w0.z, acc0.z);
            acc0.w = fmaf(v0, w0.w, acc0.w);
        }
        acc0.x += acc1.x; acc0.y += acc1.y; acc0.z += acc1.z; acc0.w += acc1.w;
        *(float4*)(x_hat + (size_t)row * D + d0) = acc0;
    }
}

// ---------------------------------------------------------------------------
extern "C" void kernel_launch(void* const* d_in, const int* in_sizes, int n_in,
                              void* d_out, int out_size, void* d_ws, size_t ws_size,
                              hipStream_t stream)
{
    const float* x     = (const float*)d_in[0];
    const float* W_enc = (const float*)d_in[1];
    const float* b_enc = (const float*)d_in[2];
    const float* W_dec = (const float*)d_in[3];
    const float* b_dec = (const float*)d_in[4];
    const int*   k_ptr = (const int*)d_in[5];

    const int F = in_sizes[2];
    const int D = in_sizes[4];
    const int B = in_sizes[0] / D;

    float* x_hat = (float*)d_out;
    float* z     = x_hat + (size_t)B * D;
    float* z_pre = z + (size_t)B * F;

    float* WdT = (float*)d_ws;                     // F*D floats
    float* wv  = WdT + (size_t)F * D;              // B*MAXK
    int*   wi  = (int*)(wv + (size_t)B * MAXK);    // B*MAXK
    char*  extra = (char*)(wi + (size_t)B * MAXK);

    const size_t base_need  = (size_t)F * D * 4 + (size_t)B * MAXK * 8;
    const size_t extra_need = (size_t)B * D * 4 + (size_t)F * D * 4;
    const bool use_pre = (ws_size >= base_need + extra_need) &&
                         (D % 32 == 0) && (B % 128 == 0) && (F % 256 == 0);

    if (use_pre) {
        ushort* AhiP = (ushort*)extra;
        ushort* AloP = AhiP + (size_t)B * D;
        ushort* WhiP = AloP + (size_t)B * D;
        ushort* WloP = WhiP + (size_t)F * D;

        prep_x_kernel<<<(B * (D / 8)) / 256, 256, 0, stream>>>(x, b_dec, AhiP, AloP, D);
        prep_w_kernel<<<(F * (D / 8)) / 256, 256, 0, stream>>>(W_enc, WhiP, WloP, D);

        const int nbm = B / 128, nbn = F / 256;
        if (D % 64 == 0) {
            encode_gemm_db<<<nbm * nbn, 256, 0, stream>>>(
                AhiP, AloP, WhiP, WloP, b_enc, z_pre, D, F, nbm);
        } else {
            encode_gemm_pre<<<dim3(nbn, nbm), 256, 0, stream>>>(
                AhiP, AloP, WhiP, WloP, b_enc, z_pre, D, F);
        }
    } else {
        encode_gemm_bf16x3<<<dim3(F / 256, B / 128), 256, 0, stream>>>(
            x, W_enc, b_enc, b_dec, z_pre, D, F);
    }

    transpose_kernel<<<dim3((F + 31) / 32, (D + 31) / 32), 256, 0, stream>>>(
        W_dec, WdT, D, F);

    const int nv4  = F / 4;
    const int nvec = (nv4 + 255) / 256;
    const bool fastok = (F <= 16384) && ((F & 3) == 0);

    if (fastok) {
        if (nvec <= 4)
            topk_fast<4><<<B, 256, 0, stream>>>(z_pre, z, wv, wi, k_ptr, x, W_enc, b_enc, b_dec, F, D);
        else if (nvec <= 8)
            topk_fast<8><<<B, 256, 0, stream>>>(z_pre, z, wv, wi, k_ptr, x, W_enc, b_enc, b_dec, F, D);
        else
            topk_fast<16><<<B, 256, 0, stream>>>(z_pre, z, wv, wi, k_ptr, x, W_enc, b_enc, b_dec, F, D);
    } else {
        if (nvec <= 8)
            topk_kernel<8><<<B, 256, 0, stream>>>(z_pre, z, wv, wi, k_ptr, x, W_enc, b_enc, b_dec, F, D);
        else if (nvec <= 16)
            topk_kernel<16><<<B, 256, 0, stream>>>(z_pre, z, wv, wi, k_ptr, x, W_enc, b_enc, b_dec, F, D);
        else
            topk_kernel<32><<<B, 256, 0, stream>>>(z_pre, z, wv, wi, k_ptr, x, W_enc, b_enc, b_dec, F, D);
    }

    decode_kernel<<<B, 256, 0, stream>>>(WdT, wv, wi, b_dec, x_hat, k_ptr, D);
}

// Round 5
// 1106.313 us; speedup vs baseline: 1.1860x; 1.1860x over previous
//
#include <hip/hip_runtime.h>
#include <cstdint>
#include <cfloat>
#include <cstddef>

#define MAXK 128

typedef __attribute__((ext_vector_type(8))) short bf16x8;
typedef __attribute__((ext_vector_type(4))) float f32x4;

// ---------------------------------------------------------------------------
// split 8 fp32 -> hi-bf16 x8 (uint4) + lo-bf16 x8 (uint4)
// ---------------------------------------------------------------------------
__device__ __forceinline__ void split8(const float4& v0, const float4& v1,
                                       uint4& hp, uint4& lp)
{
    float vv[8] = {v0.x, v0.y, v0.z, v0.w, v1.x, v1.y, v1.z, v1.w};
    unsigned h[8], l[8];
    #pragma unroll
    for (int i = 0; i < 8; ++i) {
        unsigned u  = __float_as_uint(vv[i]);
        unsigned hb = u & 0xFFFF0000u;
        float lf    = vv[i] - __uint_as_float(hb);
        h[i] = u;
        l[i] = __float_as_uint(lf);
    }
    hp.x = (h[0] >> 16) | (h[1] & 0xFFFF0000u);
    hp.y = (h[2] >> 16) | (h[3] & 0xFFFF0000u);
    hp.z = (h[4] >> 16) | (h[5] & 0xFFFF0000u);
    hp.w = (h[6] >> 16) | (h[7] & 0xFFFF0000u);
    lp.x = (l[0] >> 16) | (l[1] & 0xFFFF0000u);
    lp.y = (l[2] >> 16) | (l[3] & 0xFFFF0000u);
    lp.z = (l[4] >> 16) | (l[5] & 0xFFFF0000u);
    lp.w = (l[6] >> 16) | (l[7] & 0xFFFF0000u);
}

// async global -> LDS, 16B per lane. LDS dest = wave-uniform base + lane*16.
__device__ __forceinline__ void gload_lds16(const void* g, void* l)
{
    __builtin_amdgcn_global_load_lds(
        (const __attribute__((address_space(1))) unsigned int*)g,
        (__attribute__((address_space(3))) unsigned int*)l,
        16, 0, 0);
}

// ---------------------------------------------------------------------------
// prep_x: (x - b_dec) -> split bf16 hi/lo, tile-packed + pre-swizzled.
// ---------------------------------------------------------------------------
__global__ __launch_bounds__(256)
void prep_x_kernel(const float* __restrict__ x, const float* __restrict__ b_dec,
                   ushort* __restrict__ AhiP, ushort* __restrict__ AloP, int D)
{
    const int c   = blockIdx.x * 256 + threadIdx.x;
    const int t   = c >> 9;
    const int wc  = c & 511;
    const int rl  = wc >> 2;
    const int pkc = wc & 3;
    const int kc  = (pkc - (rl >> 1)) & 3;
    const int nkb = D >> 5;
    const int band = t / nkb, kblk = t - band * nkb;
    const int row = band * 128 + rl;
    const int k0  = kblk * 32 + kc * 8;

    const float* src = x + (size_t)row * D + k0;
    float4 v0 = *(const float4*)(src);
    float4 v1 = *(const float4*)(src + 4);
    const float* bd = b_dec + k0;
    float4 d0 = *(const float4*)(bd);
    float4 d1 = *(const float4*)(bd + 4);
    v0.x -= d0.x; v0.y -= d0.y; v0.z -= d0.z; v0.w -= d0.w;
    v1.x -= d1.x; v1.y -= d1.y; v1.z -= d1.z; v1.w -= d1.w;
    uint4 hp, lp;
    split8(v0, v1, hp, lp);
    const size_t off = (size_t)t * 4096 + (size_t)wc * 8;
    *(uint4*)&AhiP[off] = hp;
    *(uint4*)&AloP[off] = lp;
}

// ---------------------------------------------------------------------------
// prep_w: W_enc -> split bf16 hi/lo, tile-packed + pre-swizzled.
// ---------------------------------------------------------------------------
__global__ __launch_bounds__(256)
void prep_w_kernel(const float* __restrict__ Wenc,
                   ushort* __restrict__ WhiP, ushort* __restrict__ WloP, int D)
{
    const int c   = blockIdx.x * 256 + threadIdx.x;
    const int t   = c >> 10;
    const int wc  = c & 1023;
    const int rl  = wc >> 2;
    const int pkc = wc & 3;
    const int kc  = (pkc - (rl >> 1)) & 3;
    const int nkb = D >> 5;
    const int fband = t / nkb, kblk = t - fband * nkb;
    const int f   = fband * 256 + rl;
    const int k0  = kblk * 32 + kc * 8;

    const float* src = Wenc + (size_t)f * D + k0;
    float4 v0 = *(const float4*)(src);
    float4 v1 = *(const float4*)(src + 4);
    uint4 hp, lp;
    split8(v0, v1, hp, lp);
    const size_t off = (size_t)t * 8192 + (size_t)wc * 8;
    *(uint4*)&WhiP[off] = hp;
    *(uint4*)&WloP[off] = lp;
}

// ---------------------------------------------------------------------------
// Encode GEMM, pre-split operands: staging is pure global_load_lds DMA.
// 48 KB LDS -> 2 blocks/CU; inter-block overlap hides staging (proven config).
// ---------------------------------------------------------------------------
__global__ __launch_bounds__(256, 2)
void encode_gemm_pre(const ushort* __restrict__ AhiP, const ushort* __restrict__ AloP,
                     const ushort* __restrict__ WhiP, const ushort* __restrict__ WloP,
                     const float* __restrict__ b_enc, float* __restrict__ z_pre,
                     int D, int F)
{
    __shared__ ushort AsHi[4096];
    __shared__ ushort AsLo[4096];
    __shared__ ushort BsHi[8192];
    __shared__ ushort BsLo[8192];

    const int tid = threadIdx.x;
    const int bm  = blockIdx.y * 128;
    const int bn  = blockIdx.x * 256;

    const int lane = tid & 63;
    const int w    = tid >> 6;
    const int wm   = (w >> 1) * 64;
    const int wn   = (w & 1) * 128;
    const int fr   = lane & 15;
    const int q    = lane >> 4;
    const int nkb  = D >> 5;

    int aoff[4], boff[8];
    #pragma unroll
    for (int mi = 0; mi < 4; ++mi) {
        const int r = wm + mi * 16 + fr;
        aoff[mi] = r * 32 + (((q + (r >> 1)) & 3) * 8);
    }
    #pragma unroll
    for (int ni = 0; ni < 8; ++ni) {
        const int r = wn + ni * 16 + fr;
        boff[ni] = r * 32 + (((q + (r >> 1)) & 3) * 8);
    }

    f32x4 acc[4][8];
    #pragma unroll
    for (int mi = 0; mi < 4; ++mi)
        #pragma unroll
        for (int ni = 0; ni < 8; ++ni)
            acc[mi][ni] = (f32x4){0.f, 0.f, 0.f, 0.f};

    const char* aHi = (const char*)AhiP + (size_t)blockIdx.y * nkb * 8192;
    const char* aLo = (const char*)AloP + (size_t)blockIdx.y * nkb * 8192;
    const char* bHi = (const char*)WhiP + (size_t)blockIdx.x * nkb * 16384;
    const char* bLo = (const char*)WloP + (size_t)blockIdx.x * nkb * 16384;
    const int la16 = lane * 16;

    for (int kb = 0; kb < nkb; ++kb) {
        const char* pa = aHi + (size_t)kb * 8192;
        const char* pl = aLo + (size_t)kb * 8192;
        const char* pb = bHi + (size_t)kb * 16384;
        const char* pm = bLo + (size_t)kb * 16384;

        #pragma unroll
        for (int c = 0; c < 2; ++c) {
            const int off = (w * 2 + c) * 1024;
            gload_lds16(pa + off + la16, (char*)AsHi + off);
            gload_lds16(pl + off + la16, (char*)AsLo + off);
        }
        #pragma unroll
        for (int c = 0; c < 4; ++c) {
            const int off = (w * 4 + c) * 1024;
            gload_lds16(pb + off + la16, (char*)BsHi + off);
            gload_lds16(pm + off + la16, (char*)BsLo + off);
        }
        asm volatile("s_waitcnt vmcnt(0)" ::: "memory");
        __syncthreads();

        bf16x8 ahi[4], alo[4];
        #pragma unroll
        for (int mi = 0; mi < 4; ++mi) {
            ahi[mi] = *(const bf16x8*)&AsHi[aoff[mi]];
            alo[mi] = *(const bf16x8*)&AsLo[aoff[mi]];
        }
        #pragma unroll
        for (int ni = 0; ni < 8; ++ni) {
            bf16x8 bhi = *(const bf16x8*)&BsHi[boff[ni]];
            bf16x8 blo = *(const bf16x8*)&BsLo[boff[ni]];
            #pragma unroll
            for (int mi = 0; mi < 4; ++mi) {
                acc[mi][ni] = __builtin_amdgcn_mfma_f32_16x16x32_bf16(alo[mi], bhi, acc[mi][ni], 0, 0, 0);
                acc[mi][ni] = __builtin_amdgcn_mfma_f32_16x16x32_bf16(ahi[mi], blo, acc[mi][ni], 0, 0, 0);
                acc[mi][ni] = __builtin_amdgcn_mfma_f32_16x16x32_bf16(ahi[mi], bhi, acc[mi][ni], 0, 0, 0);
            }
        }
        __syncthreads();
    }

    #pragma unroll
    for (int ni = 0; ni < 8; ++ni) {
        const int col = bn + wn + ni * 16 + fr;
        const float be = b_enc[col];
        #pragma unroll
        for (int mi = 0; mi < 4; ++mi) {
            const int rbase = bm + wm + mi * 16 + q * 4;
            float* dst = z_pre + (size_t)rbase * F + col;
            #pragma unroll
            for (int r = 0; r < 4; ++r)
                dst[(size_t)r * F] = acc[mi][ni][r] + be;
        }
    }
}

// ---------------------------------------------------------------------------
// Fallback encode GEMM (reg-staged split) — used only if workspace too small.
// ---------------------------------------------------------------------------
__global__ __launch_bounds__(256, 2)
void encode_gemm_bf16x3(const float* __restrict__ x, const float* __restrict__ Wenc,
                        const float* __restrict__ b_enc, const float* __restrict__ b_dec,
                        float* __restrict__ z_pre, int D, int F)
{
    constexpr int BM = 128, BN = 256, BK = 32;
    __shared__ ushort AsHi[BM * BK];
    __shared__ ushort AsLo[BM * BK];
    __shared__ ushort BsHi[BN * BK];
    __shared__ ushort BsLo[BN * BK];

    const int tid = threadIdx.x;
    const int bm  = blockIdx.y * BM;
    const int bn  = blockIdx.x * BN;

    const int lane = tid & 63;
    const int w    = tid >> 6;
    const int wm   = (w >> 1) * 64;
    const int wn   = (w & 1) * 128;
    const int fr   = lane & 15;
    const int q    = lane >> 4;

    int aoff[4], boff[8];
    #pragma unroll
    for (int mi = 0; mi < 4; ++mi) {
        const int r = wm + mi * 16 + fr;
        aoff[mi] = r * 32 + (((q + (r >> 1)) & 3) * 8);
    }
    #pragma unroll
    for (int ni = 0; ni < 8; ++ni) {
        const int r = wn + ni * 16 + fr;
        boff[ni] = r * 32 + (((q + (r >> 1)) & 3) * 8);
    }

    f32x4 acc[4][8];
    #pragma unroll
    for (int mi = 0; mi < 4; ++mi)
        #pragma unroll
        for (int ni = 0; ni < 8; ++ni)
            acc[mi][ni] = (f32x4){0.f, 0.f, 0.f, 0.f};

    for (int k0 = 0; k0 < D; k0 += BK) {
        #pragma unroll
        for (int j = 0; j < 2; ++j) {
            const int task = tid + 256 * j;
            const int row = task >> 2, kc = task & 3;
            const float* src = x + (size_t)(bm + row) * D + k0 + kc * 8;
            float4 v0 = *(const float4*)(src);
            float4 v1 = *(const float4*)(src + 4);
            const float* bd = b_dec + k0 + kc * 8;
            float4 d0 = *(const float4*)(bd);
            float4 d1 = *(const float4*)(bd + 4);
            v0.x -= d0.x; v0.y -= d0.y; v0.z -= d0.z; v0.w -= d0.w;
            v1.x -= d1.x; v1.y -= d1.y; v1.z -= d1.z; v1.w -= d1.w;
            uint4 hp, lp;
            split8(v0, v1, hp, lp);
            const int off = row * 32 + (((kc + (row >> 1)) & 3) * 8);
            *(uint4*)&AsHi[off] = hp;
            *(uint4*)&AsLo[off] = lp;
        }
        #pragma unroll
        for (int j = 0; j < 4; ++j) {
            const int task = tid + 256 * j;
            const int row = task >> 2, kc = task & 3;
            const float* src = Wenc + (size_t)(bn + row) * D + k0 + kc * 8;
            float4 v0 = *(const float4*)(src);
            float4 v1 = *(const float4*)(src + 4);
            uint4 hp, lp;
            split8(v0, v1, hp, lp);
            const int off = row * 32 + (((kc + (row >> 1)) & 3) * 8);
            *(uint4*)&BsHi[off] = hp;
            *(uint4*)&BsLo[off] = lp;
        }
        __syncthreads();

        bf16x8 ahi[4], alo[4];
        #pragma unroll
        for (int mi = 0; mi < 4; ++mi) {
            ahi[mi] = *(const bf16x8*)&AsHi[aoff[mi]];
            alo[mi] = *(const bf16x8*)&AsLo[aoff[mi]];
        }
        #pragma unroll
        for (int ni = 0; ni < 8; ++ni) {
            bf16x8 bhi = *(const bf16x8*)&BsHi[boff[ni]];
            bf16x8 blo = *(const bf16x8*)&BsLo[boff[ni]];
            #pragma unroll
            for (int mi = 0; mi < 4; ++mi) {
                acc[mi][ni] = __builtin_amdgcn_mfma_f32_16x16x32_bf16(alo[mi], bhi, acc[mi][ni], 0, 0, 0);
                acc[mi][ni] = __builtin_amdgcn_mfma_f32_16x16x32_bf16(ahi[mi], blo, acc[mi][ni], 0, 0, 0);
                acc[mi][ni] = __builtin_amdgcn_mfma_f32_16x16x32_bf16(ahi[mi], bhi, acc[mi][ni], 0, 0, 0);
            }
        }
        __syncthreads();
    }

    #pragma unroll
    for (int ni = 0; ni < 8; ++ni) {
        const int col = bn + wn + ni * 16 + fr;
        const float be = b_enc[col];
        #pragma unroll
        for (int mi = 0; mi < 4; ++mi) {
            const int rbase = bm + wm + mi * 16 + q * 4;
            float* dst = z_pre + (size_t)rbase * F + col;
            #pragma unroll
            for (int r = 0; r < 4; ++r)
                dst[(size_t)r * F] = acc[mi][ni][r] + be;
        }
    }
}

// ---------------------------------------------------------------------------
// Monotonic uint key for float ordering
// ---------------------------------------------------------------------------
__device__ __forceinline__ unsigned fkey(float f)
{
    unsigned u = __float_as_uint(f);
    return u ^ ((unsigned)((int)u >> 31) | 0x80000000u);
}
__device__ __forceinline__ float finv(unsigned k)
{
    unsigned u = (k & 0x80000000u) ? (k ^ 0x80000000u) : ~k;
    return __uint_as_float(u);
}

// exact fp32 dot for feature f over one wave; valid result on ln==0 only
__device__ __forceinline__ float exact_zpre(const float* __restrict__ xr,
                                            const float* __restrict__ Wenc,
                                            const float* __restrict__ b_enc,
                                            const float* __restrict__ b_dec,
                                            int f, int D, int ln)
{
    const float* wr = Wenc + (size_t)f * D;
    float s = 0.f;
    for (int d = ln * 4; d < D; d += 256) {
        float4 xv = *(const float4*)(xr + d);
        float4 bd = *(const float4*)(b_dec + d);
        float4 wv4 = *(const float4*)(wr + d);
        s = fmaf(xv.x - bd.x, wv4.x, s);
        s = fmaf(xv.y - bd.y, wv4.y, s);
        s = fmaf(xv.z - bd.z, wv4.z, s);
        s = fmaf(xv.w - bd.w, wv4.w, s);
    }
    #pragma unroll
    for (int o = 32; o > 0; o >>= 1) s += __shfl_down(s, o, 64);
    return s + b_enc[f];
}

// ---------------------------------------------------------------------------
// topk_fast: single-stream top-k (zero-fill of z fused into pass 1).
// ---------------------------------------------------------------------------
#define DLT 4e-3f

template <int NVEC>
__global__ __launch_bounds__(256)
void topk_fast(const float* __restrict__ z_pre, float* __restrict__ z,
               float* __restrict__ ws_vals, int* __restrict__ ws_idx,
               const int* __restrict__ k_ptr,
               const float* __restrict__ x, const float* __restrict__ Wenc,
               const float* __restrict__ b_enc, const float* __restrict__ b_dec,
               int F, int D)
{
    const int row = blockIdx.x;
    const int t   = threadIdx.x;
    const int k   = *k_ptr;
    const int nv4 = F >> 2;
    const int wv_id = t >> 6, ln = t & 63;

    __shared__ ushort keys[16384];          // 32 KB
    __shared__ float  cand_v[256];
    __shared__ int    cand_i[256];
    __shared__ unsigned char cand_sel[256];
    __shared__ int    bnd[128];
    __shared__ float  s2w[4];
    __shared__ int    hist4[4][256];        // fallback only
    __shared__ int    waveTot[4];
    __shared__ int    s_bin, s_above;
    __shared__ int    n_c_s, n_b_s, c_hi_s, out_cnt, cnt_tau_s, bad_s;
    __shared__ unsigned vk_key;

    if (t == 0) {
        n_c_s = 0; n_b_s = 0; c_hi_s = 0; out_cnt = 0; cnt_tau_s = 0; bad_s = 0;
        vk_key = 0xFFFFFFFFu;
    }

    const float*  zrow = z_pre + (size_t)row * F;
    const float4* src  = (const float4*)zrow;
    float4* dstz = (float4*)(z + (size_t)row * F);
    const float4 zz = make_float4(0.f, 0.f, 0.f, 0.f);

    // ---- pass 1: stream z_pre once: sum v^2 + bf16 keys to LDS + z zero-fill
    float s2 = 0.f;
    #pragma unroll
    for (int i = 0; i < NVEC; ++i) {
        const int p = t + 256 * i;
        if (p < nv4) {
            const float4 v = src[p];
            dstz[p] = zz;                   // overlapped with read stream
            const unsigned k0 = fkey(v.x) >> 16;
            const unsigned k1 = fkey(v.y) >> 16;
            const unsigned k2 = fkey(v.z) >> 16;
            const unsigned k3 = fkey(v.w) >> 16;
            uint2 pk;
            pk.x = k0 | (k1 << 16);
            pk.y = k2 | (k3 << 16);
            *(uint2*)&keys[p * 4] = pk;
            s2 = fmaf(v.x, v.x, s2);
            s2 = fmaf(v.y, v.y, s2);
            s2 = fmaf(v.z, v.z, s2);
            s2 = fmaf(v.w, v.w, s2);
        }
    }
    #pragma unroll
    for (int o = 32; o > 0; o >>= 1) s2 += __shfl_down(s2, o, 64);
    if (ln == 0) s2w[wv_id] = s2;
    __syncthreads();

    const float sigma = sqrtf((s2w[0] + s2w[1] + s2w[2] + s2w[3]) / (float)F);
    int c0 = 4 * k; if (c0 < 64) c0 = 64; if (c0 > 192) c0 = 192;
    const float qq  = (float)c0 / (float)F;
    const float tt  = sqrtf(-2.f * logf(qq));
    const float phi = tt - (2.30753f + 0.27061f * tt) /
                           (1.f + 0.99229f * tt + 0.04481f * tt * tt);
    const float tau = sigma * phi;
    const unsigned tk = fkey(tau) >> 16;
    const unsigned tkey16 = (tk >= 2) ? (tk - 2) : 0;

    // ---- pass 2: scan LDS keys, collect candidate indices ----
    const int nU = nv4 * 2;
    const unsigned* keysU = (const unsigned*)keys;
    for (int j = t; j < nU; j += 256) {
        const unsigned pr = keysU[j];
        const unsigned ka = pr & 0xFFFFu, kb = pr >> 16;
        if (ka > tkey16) { const int s = atomicAdd(&n_c_s, 1); if (s < 256) cand_i[s] = 2 * j; }
        if (kb > tkey16) { const int s = atomicAdd(&n_c_s, 1); if (s < 256) cand_i[s] = 2 * j + 1; }
    }
    __syncthreads();

    if (t == 0 && (n_c_s > 256 || !(tau > 0.1f))) bad_s = 1;
    const int n_c = min(n_c_s, 256);

    float myv = 0.f;
    if (t < n_c) {
        myv = zrow[cand_i[t]];
        cand_v[t] = myv;
        if (myv > tau) atomicAdd(&cnt_tau_s, 1);
    }
    __syncthreads();
    if (t == 0 && cnt_tau_s < k) bad_s = 1;

    cand_sel[t] = 0;
    if (t < n_c) {
        int gt = 0;
        for (int j = 0; j < n_c; ++j) gt += (cand_v[j] > myv);
        if (gt <= k - 1) atomicMin(&vk_key, fkey(myv));
    }
    __syncthreads();

    const float vkv = finv(vk_key);
    if (t < n_c) {
        if (myv > vkv + DLT) {
            cand_sel[t] = 2;
            atomicAdd(&c_hi_s, 1);
        } else if (myv > vkv - DLT) {
            const int sb = atomicAdd(&n_b_s, 1);
            if (sb < 128) bnd[sb] = t;
        }
    }
    __syncthreads();
    if (t == 0 && n_b_s > 128) bad_s = 1;
    __syncthreads();

    if (!bad_s) {
        const int n_b = n_b_s;
        const float* xr = x + (size_t)row * D;
        for (int b2 = wv_id; b2 < n_b; b2 += 4) {
            const int c = bnd[b2];
            const float ex = exact_zpre(xr, Wenc, b_enc, b_dec, cand_i[c], D, ln);
            if (ln == 0) cand_v[c] = ex;
        }
        __syncthreads();

        if (t == 0) {
            int need = k - c_hi_s;
            if (need > n_b) need = n_b;
            for (int it = 0; it < need; ++it) {
                int bi = -1; float bv = 0.f;
                for (int b2 = 0; b2 < n_b; ++b2) {
                    const int c = bnd[b2];
                    if (cand_sel[c]) continue;
                    const float v = cand_v[c];
                    if (bi < 0 || v > bv || (v == bv && cand_i[c] < cand_i[bi])) {
                        bi = c; bv = v;
                    }
                }
                if (bi < 0) break;
                cand_sel[bi] = 1;
            }
        }
        __syncthreads();

        float* wvp = ws_vals + (size_t)row * MAXK;
        int*   wip = ws_idx  + (size_t)row * MAXK;
        if (t < n_c && cand_sel[t]) {
            const float zv = fmaxf(cand_v[t], 0.f);
            z[(size_t)row * F + cand_i[t]] = zv;
            const int s = atomicAdd(&out_cnt, 1);
            if (s < MAXK) { wvp[s] = zv; wip[s] = cand_i[t]; }
        }
        return;
    }

    // ================= fallback: 2-pass radix on global fp32 =================
    if (t == 0) { n_c_s = 0; c_hi_s = 0; out_cnt = 0; }
    __syncthreads();

    unsigned prefix = 0;
    int rem = k;
    for (int pass = 0; pass < 2; ++pass) {
        const int shift = 24 - 8 * pass;
        hist4[0][t] = 0; hist4[1][t] = 0; hist4[2][t] = 0; hist4[3][t] = 0;
        __syncthreads();
        for (int j = t; j < F; j += 256) {
            const unsigned key = fkey(zrow[j]);
            const bool inb = (pass == 0) || ((key >> (shift + 8)) == prefix);
            if (inb) atomicAdd(&hist4[wv_id][(key >> shift) & 255], 1);
        }
        __syncthreads();
        const int cnt = hist4[0][t] + hist4[1][t] + hist4[2][t] + hist4[3][t];
        int s = cnt;
        #pragma unroll
        for (int off = 1; off < 64; off <<= 1) {
            const int tmp = __shfl_down(s, off, 64);
            if (ln + off < 64) s += tmp;
        }
        if (ln == 0) waveTot[wv_id] = s;
        __syncthreads();
        int add = 0;
        #pragma unroll
        for (int w2 = 0; w2 < 4; ++w2)
            if (w2 > wv_id) add += waveTot[w2];
        const int sfx = s + add;
        const int nxt = sfx - cnt;
        if (sfx >= rem && nxt < rem) { s_bin = t; s_above = nxt; }
        __syncthreads();
        rem -= s_above;
        prefix = (prefix << 8) | (unsigned)s_bin;
        __syncthreads();
    }

    const float hiT = finv((prefix << 16) | 0xFFFFu) + DLT;
    const float loT = finv(prefix << 16) - DLT;

    for (int j = t; j < F; j += 256) {
        const float v = zrow[j];
        if (v > hiT) atomicAdd(&c_hi_s, 1);
        else if (v > loT) {
            const int s = atomicAdd(&n_c_s, 1);
            if (s < 256) { cand_i[s] = j; cand_sel[s] = 0; }
        }
    }
    __syncthreads();
    const int n_c2 = min(n_c_s, 256);

    {
        const float* xr = x + (size_t)row * D;
        for (int c = wv_id; c < n_c2; c += 4) {
            const float ex = exact_zpre(xr, Wenc, b_enc, b_dec, cand_i[c], D, ln);
            if (ln == 0) cand_v[c] = ex;
        }
    }
    __syncthreads();

    if (t == 0) {
        int need = k - c_hi_s;
        if (need > n_c2) need = n_c2;
        for (int it = 0; it < need; ++it) {
            int bi = -1; float bv = 0.f;
            for (int c = 0; c < n_c2; ++c) {
                if (cand_sel[c]) continue;
                const float v = cand_v[c];
                if (bi < 0 || v > bv || (v == bv && cand_i[c] < cand_i[bi])) {
                    bi = c; bv = v;
                }
            }
            if (bi < 0) break;
            cand_sel[bi] = 1;
        }
    }
    __syncthreads();

    {
        const float4 z4 = make_float4(0.f, 0.f, 0.f, 0.f);
        #pragma unroll
        for (int i = 0; i < NVEC; ++i) {
            const int p = t + 256 * i;
            if (p < nv4) dstz[p] = z4;
        }
    }
    __syncthreads();

    float* wvp = ws_vals + (size_t)row * MAXK;
    int*   wip = ws_idx  + (size_t)row * MAXK;
    for (int j = t; j < F; j += 256) {
        const float v = zrow[j];
        if (v > hiT) {
            const float zv = fmaxf(v, 0.f);
            z[(size_t)row * F + j] = zv;
            const int s = atomicAdd(&out_cnt, 1);
            if (s < MAXK) { wvp[s] = zv; wip[s] = j; }
        }
    }
    if (t < n_c2 && cand_sel[t]) {
        const float zv = fmaxf(cand_v[t], 0.f);
        z[(size_t)row * F + cand_i[t]] = zv;
        const int s = atomicAdd(&out_cnt, 1);
        if (s < MAXK) { wvp[s] = zv; wip[s] = cand_i[t]; }
    }
}

// ---------------------------------------------------------------------------
// Generic per-row top-k — only for F > 16384.
// ---------------------------------------------------------------------------
template <int NVEC>
__global__ __launch_bounds__(256)
void topk_kernel(const float* __restrict__ z_pre, float* __restrict__ z,
                 float* __restrict__ ws_vals, int* __restrict__ ws_idx,
                 const int* __restrict__ k_ptr,
                 const float* __restrict__ x, const float* __restrict__ Wenc,
                 const float* __restrict__ b_enc, const float* __restrict__ b_dec,
                 int F, int D)
{
    const int row = blockIdx.x;
    const int t   = threadIdx.x;
    const int k   = *k_ptr;
    const int nv4 = F >> 2;
    const int wv_id = t >> 6;
    const int ln    = t & 63;

    const float4* src = (const float4*)(z_pre + (size_t)row * F);
    float4 vals[NVEC];
    #pragma unroll
    for (int i = 0; i < NVEC; ++i) {
        const int p = t + 256 * i;
        if (p < nv4) vals[i] = src[p];
        else         vals[i] = make_float4(-FLT_MAX, -FLT_MAX, -FLT_MAX, -FLT_MAX);
    }

    __shared__ int hist[4][256];
    __shared__ int waveTot[4];
    __shared__ int s_bin, s_above;
    __shared__ int c_hi_s, n_c_s, out_cnt;
    __shared__ int cand_idx[128];
    __shared__ float cand_val[128];
    __shared__ unsigned char cand_sel[128];

    unsigned prefix = 0;
    int rem = k;

    #pragma unroll
    for (int pass = 0; pass < 2; ++pass) {
        const int shift = 24 - 8 * pass;
        hist[0][t] = 0; hist[1][t] = 0; hist[2][t] = 0; hist[3][t] = 0;
        __syncthreads();
        #pragma unroll
        for (int i = 0; i < NVEC; ++i) {
            const float* vv = (const float*)&vals[i];
            #pragma unroll
            for (int j = 0; j < 4; ++j) {
                const unsigned key = fkey(vv[j]);
                const bool inb = (pass == 0) || ((key >> (shift + 8)) == prefix);
                if (inb) atomicAdd(&hist[wv_id][(key >> shift) & 255], 1);
            }
        }
        __syncthreads();
        const int cnt = hist[0][t] + hist[1][t] + hist[2][t] + hist[3][t];
        int s = cnt;
        #pragma unroll
        for (int off = 1; off < 64; off <<= 1) {
            const int tmp = __shfl_down(s, off, 64);
            if (ln + off < 64) s += tmp;
        }
        if (ln == 0) waveTot[wv_id] = s;
        __syncthreads();
        int add = 0;
        #pragma unroll
        for (int w2 = 0; w2 < 4; ++w2)
            if (w2 > wv_id) add += waveTot[w2];
        const int sfx = s + add;
        const int nxt = sfx - cnt;
        if (sfx >= rem && nxt < rem) { s_bin = t; s_above = nxt; }
        __syncthreads();
        rem -= s_above;
        prefix = (prefix << 8) | (unsigned)s_bin;
        __syncthreads();
    }

    const unsigned keyLo = prefix << 16;
    const unsigned keyHi = keyLo | 0xFFFFu;
    const float dlt = 1e-3f;
    const float hiThr = finv(keyHi) + dlt;
    const float loThr = finv(keyLo) - dlt;

    if (t == 0) { c_hi_s = 0; n_c_s = 0; out_cnt = 0; }
    __syncthreads();

    #pragma unroll
    for (int i = 0; i < NVEC; ++i) {
        const float* vv = (const float*)&vals[i];
        #pragma unroll
        for (int j = 0; j < 4; ++j) {
            const float v = vv[j];
            if (v > hiThr) {
                atomicAdd(&c_hi_s, 1);
            } else if (v > loThr) {
                const int s = atomicAdd(&n_c_s, 1);
                if (s < 128) { cand_idx[s] = (t + 256 * i) * 4 + j; cand_sel[s] = 0; }
            }
        }
    }
    __syncthreads();

    const int n_c = min(n_c_s, 128);

    {
        const float* xr = x + (size_t)row * D;
        for (int c = wv_id; c < n_c; c += 4) {
            const float ex = exact_zpre(xr, Wenc, b_enc, b_dec, cand_idx[c], D, ln);
            if (ln == 0) cand_val[c] = ex;
        }
    }
    __syncthreads();

    if (t == 0) {
        int need = k - c_hi_s;
        if (need > n_c) need = n_c;
        for (int it = 0; it < need; ++it) {
            int bi = -1; float bv = 0.f;
            for (int c = 0; c < n_c; ++c) {
                if (cand_sel[c]) continue;
                const float v = cand_val[c];
                if (bi < 0 || v > bv || (v == bv && cand_idx[c] < cand_idx[bi])) {
                    bi = c; bv = v;
                }
            }
            if (bi < 0) break;
            cand_sel[bi] = 1;
        }
    }
    __syncthreads();

    float4* dstz = (float4*)(z + (size_t)row * F);
    float*  wv   = ws_vals + (size_t)row * MAXK;
    int*    wi   = ws_idx  + (size_t)row * MAXK;

    #pragma unroll
    for (int i = 0; i < NVEC; ++i) {
        const int p4 = t + 256 * i;
        if (p4 < nv4) {
            const float* vv = (const float*)&vals[i];
            float4 outv;
            float* ov = (float*)&outv;
            #pragma unroll
            for (int j = 0; j < 4; ++j) {
                const int pos = p4 * 4 + j;
                const float v = vv[j];
                float zv = 0.f;
                bool sel = false;
                if (v > hiThr) {
                    zv = fmaxf(v, 0.f); sel = true;
                } else if (v > loThr) {
                    for (int c = 0; c < n_c; ++c) {
                        if (cand_idx[c] == pos) {
                            if (cand_sel[c]) { zv = fmaxf(cand_val[c], 0.f); sel = true; }
                            break;
                        }
                    }
                }
                ov[j] = zv;
                if (sel) {
                    const int s = atomicAdd(&out_cnt, 1);
                    if (s < MAXK) { wv[s] = zv; wi[s] = pos; }
                }
            }
            dstz[p4] = outv;
        }
    }
}

// ---------------------------------------------------------------------------
// Transpose W_dec [R, C] -> out [C, R], float4 on BOTH global sides.
// 64x64 tile, 256 threads, tile[64][65] (<=2-way LDS aliasing = free).
// Requires R%64==0 && C%64==0 (else use scalar fallback kernel).
// ---------------------------------------------------------------------------
__global__ __launch_bounds__(256)
void transpose4_kernel(const float* __restrict__ in, float* __restrict__ out,
                       int R, int C)
{
    __shared__ float tile[64][65];
    const int c0 = blockIdx.x * 64;
    const int r0 = blockIdx.y * 64;
    const int t  = threadIdx.x;
    const int tc = (t & 15) * 4;      // 4-col group within tile
    const int tr = t >> 4;            // 0..15

    #pragma unroll
    for (int i = 0; i < 4; ++i) {
        const int r = tr + i * 16;
        const float4 v = *(const float4*)(in + (size_t)(r0 + r) * C + c0 + tc);
        tile[r][tc]     = v.x;
        tile[r][tc + 1] = v.y;
        tile[r][tc + 2] = v.z;
        tile[r][tc + 3] = v.w;
    }
    __syncthreads();
    #pragma unroll
    for (int i = 0; i < 4; ++i) {
        const int c = tr + i * 16;
        float4 v;
        v.x = tile[tc]    [c];
        v.y = tile[tc + 1][c];
        v.z = tile[tc + 2][c];
        v.w = tile[tc + 3][c];
        *(float4*)(out + (size_t)(c0 + c) * R + r0 + tc) = v;
    }
}

__global__ __launch_bounds__(256)
void transpose_kernel(const float* __restrict__ in, float* __restrict__ out,
                      int R, int C)
{
    __shared__ float tile[32][33];
    const int c0 = blockIdx.x * 32;
    const int r0 = blockIdx.y * 32;
    const int tx = threadIdx.x & 31;
    const int ty = threadIdx.x >> 5;

    #pragma unroll
    for (int i = ty; i < 32; i += 8) {
        const int r = r0 + i, c = c0 + tx;
        tile[i][tx] = (r < R && c < C) ? in[(size_t)r * C + c] : 0.f;
    }
    __syncthreads();
    #pragma unroll
    for (int i = ty; i < 32; i += 8) {
        const int c = c0 + i, r = r0 + tx;
        if (c < C && r < R) out[(size_t)c * R + r] = tile[tx][i];
    }
}

// ---------------------------------------------------------------------------
// Sparse decode: x_hat[b,:] = b_dec + sum_j val_j * W_decT[idx_j,:]
// (val,idx) in LDS; 4-way unroll + 4 accumulators for gather MLP.
// ---------------------------------------------------------------------------
__global__ __launch_bounds__(256)
void decode_kernel(const float* __restrict__ WdT, const float* __restrict__ wvals,
                   const int* __restrict__ widx, const float* __restrict__ b_dec,
                   float* __restrict__ x_hat, const int* __restrict__ k_ptr, int D)
{
    __shared__ float sv[MAXK];
    __shared__ int   si[MAXK];
    const int row = blockIdx.x;
    const int t   = threadIdx.x;
    int k = *k_ptr;
    if (k > MAXK) k = MAXK;

    if (t < MAXK) {
        sv[t] = wvals[(size_t)row * MAXK + t];
        si[t] = widx [(size_t)row * MAXK + t];
    }
    __syncthreads();

    for (int d0 = t * 4; d0 < D; d0 += 1024) {
        float4 a0 = *(const float4*)(b_dec + d0);
        float4 a1 = make_float4(0.f, 0.f, 0.f, 0.f);
        float4 a2 = make_float4(0.f, 0.f, 0.f, 0.f);
        float4 a3 = make_float4(0.f, 0.f, 0.f, 0.f);
        int j = 0;
        for (; j + 4 <= k; j += 4) {
            const float v0 = sv[j], v1 = sv[j+1], v2 = sv[j+2], v3 = sv[j+3];
            const float4 w0 = *(const float4*)(WdT + (size_t)si[j]   * D + d0);
            const float4 w1 = *(const float4*)(WdT + (size_t)si[j+1] * D + d0);
            const float4 w2 = *(const float4*)(WdT + (size_t)si[j+2] * D + d0);
            const float4 w3 = *(const float4*)(WdT + (size_t)si[j+3] * D + d0);
            a0.x = fmaf(v0, w0.x, a0.x); a0.y = fmaf(v0, w0.y, a0.y);
            a0.z = fmaf(v0, w0.z, a0.z); a0.w = fmaf(v0, w0.w, a0.w);
            a1.x = fmaf(v1, w1.x, a1.x); a1.y = fmaf(v1, w1.y, a1.y);
            a1.z = fmaf(v1, w1.z, a1.z); a1.w = fmaf(v1, w1.w, a1.w);
            a2.x = fmaf(v2, w2.x, a2.x); a2.y = fmaf(v2, w2.y, a2.y);
            a2.z = fmaf(v2, w2.z, a2.z); a2.w = fmaf(v2, w2.w, a2.w);
            a3.x = fmaf(v3, w3.x, a3.x); a3.y = fmaf(v3, w3.y, a3.y);
            a3.z = fmaf(v3, w3.z, a3.z); a3.w = fmaf(v3, w3.w, a3.w);
        }
        for (; j < k; ++j) {
            const float v0 = sv[j];
            const float4 w0 = *(const float4*)(WdT + (size_t)si[j] * D + d0);
            a0.x = fmaf(v0, w0.x, a0.x); a0.y = fmaf(v0, w0.y, a0.y);
            a0.z = fmaf(v0, w0.z, a0.z); a0.w = fmaf(v0, w0.w, a0.w);
        }
        a0.x += a1.x + a2.x + a3.x;
        a0.y += a1.y + a2.y + a3.y;
        a0.z += a1.z + a2.z + a3.z;
        a0.w += a1.w + a2.w + a3.w;
        *(float4*)(x_hat + (size_t)row * D + d0) = a0;
    }
}

// ---------------------------------------------------------------------------
extern "C" void kernel_launch(void* const* d_in, const int* in_sizes, int n_in,
                              void* d_out, int out_size, void* d_ws, size_t ws_size,
                              hipStream_t stream)
{
    const float* x     = (const float*)d_in[0];
    const float* W_enc = (const float*)d_in[1];
    const float* b_enc = (const float*)d_in[2];
    const float* W_dec = (const float*)d_in[3];
    const float* b_dec = (const float*)d_in[4];
    const int*   k_ptr = (const int*)d_in[5];

    const int F = in_sizes[2];
    const int D = in_sizes[4];
    const int B = in_sizes[0] / D;

    float* x_hat = (float*)d_out;
    float* z     = x_hat + (size_t)B * D;
    float* z_pre = z + (size_t)B * F;

    float* WdT = (float*)d_ws;                     // F*D floats
    float* wv  = WdT + (size_t)F * D;              // B*MAXK
    int*   wi  = (int*)(wv + (size_t)B * MAXK);    // B*MAXK
    char*  extra = (char*)(wi + (size_t)B * MAXK);

    const size_t base_need  = (size_t)F * D * 4 + (size_t)B * MAXK * 8;
    const size_t extra_need = (size_t)B * D * 4 + (size_t)F * D * 4;
    const bool use_pre = (ws_size >= base_need + extra_need) &&
                         (D % 32 == 0) && (B % 128 == 0) && (F % 256 == 0);

    if (use_pre) {
        ushort* AhiP = (ushort*)extra;
        ushort* AloP = AhiP + (size_t)B * D;
        ushort* WhiP = AloP + (size_t)B * D;
        ushort* WloP = WhiP + (size_t)F * D;

        prep_x_kernel<<<(B * (D / 8)) / 256, 256, 0, stream>>>(x, b_dec, AhiP, AloP, D);
        prep_w_kernel<<<(F * (D / 8)) / 256, 256, 0, stream>>>(W_enc, WhiP, WloP, D);
        encode_gemm_pre<<<dim3(F / 256, B / 128), 256, 0, stream>>>(
            AhiP, AloP, WhiP, WloP, b_enc, z_pre, D, F);
    } else {
        encode_gemm_bf16x3<<<dim3(F / 256, B / 128), 256, 0, stream>>>(
            x, W_enc, b_enc, b_dec, z_pre, D, F);
    }

    if ((D % 64 == 0) && (F % 64 == 0)) {
        transpose4_kernel<<<dim3(F / 64, D / 64), 256, 0, stream>>>(
            W_dec, WdT, D, F);
    } else {
        transpose_kernel<<<dim3((F + 31) / 32, (D + 31) / 32), 256, 0, stream>>>(
            W_dec, WdT, D, F);
    }

    const int nv4  = F / 4;
    const int nvec = (nv4 + 255) / 256;
    const bool fastok = (F <= 16384) && ((F & 3) == 0);

    if (fastok) {
        if (nvec <= 4)
            topk_fast<4><<<B, 256, 0, stream>>>(z_pre, z, wv, wi, k_ptr, x, W_enc, b_enc, b_dec, F, D);
        else if (nvec <= 8)
            topk_fast<8><<<B, 256, 0, stream>>>(z_pre, z, wv, wi, k_ptr, x, W_enc, b_enc, b_dec, F, D);
        else
            topk_fast<16><<<B, 256, 0, stream>>>(z_pre, z, wv, wi, k_ptr, x, W_enc, b_enc, b_dec, F, D);
    } else {
        if (nvec <= 8)
            topk_kernel<8><<<B, 256, 0, stream>>>(z_pre, z, wv, wi, k_ptr, x, W_enc, b_enc, b_dec, F, D);
        else if (nvec <= 16)
            topk_kernel<16><<<B, 256, 0, stream>>>(z_pre, z, wv, wi, k_ptr, x, W_enc, b_enc, b_dec, F, D);
        else
            topk_kernel<32><<<B, 256, 0, stream>>>(z_pre, z, wv, wi, k_ptr, x, W_enc, b_enc, b_dec, F, D);
    }

    decode_kernel<<<B, 256, 0, stream>>>(WdT, wv, wi, b_dec, x_hat, k_ptr, D);
}